// Round 5
// baseline (1121.253 us; speedup 1.0000x reference)
//
#include <hip/hip_runtime.h>

static const int kN = 50000;   // nodes
static const int kE = 300000;  // edges
static const int kG = 2048;    // graphs
static const int kT = 19;      // targets
static const int kSeg = kN * 4;  // CSR segments: key = dst*4 + rel
static const int kScanB = (kSeg + 256) / 256;  // 784 blocks covers kSeg+1

typedef __bf16 bf16;
typedef __bf16 bf16x8 __attribute__((ext_vector_type(8)));
typedef __bf16 bf16x4 __attribute__((ext_vector_type(4)));
typedef float  f32x4  __attribute__((ext_vector_type(4)));

// Fragment-linear element index for an [*,1024]-like matrix consumed as MFMA
// A-operand: element (row,k) -> ((row>>4)*KSR + (k>>5))*512 + ((k>>3)&3)*128
// + (row&15)*8 + (k&7), KSR = K/32. A wave's frag load is then lane*8 within
// one 512-elem block: 64 lanes x 16B contiguous (1 KB burst).
__device__ __forceinline__ long fragA_idx(int row, int k, int KSR) {
    return ((long)(row >> 4) * KSR + (k >> 5)) * 512
         + ((k >> 3) & 3) * 128 + (row & 15) * 8 + (k & 7);
}

// ---------------------------------------------------------------------------
// GEMM1 layers 2/3: aggregate (CSR, +self) into LDS, then MFMA vs w1t[r].
// Grid (ceil(N/64), 4=rel), 512 threads (8 waves). h1 written FRAG-LINEAR.
// ---------------------------------------------------------------------------
__global__ __launch_bounds__(512) void k_rgin1(
    const bf16* __restrict__ Pb, const int* __restrict__ srcidx,
    const int* __restrict__ row_ptr, const bf16* __restrict__ w1t,
    bf16* __restrict__ h1F, float* __restrict__ stats)
{
    __shared__ bf16 As[64][264];   // row stride 264 bf16 = 132 dwords
    const int t = threadIdx.x;
    const int r = blockIdx.y;
    const int m0 = blockIdx.x * 64;
    const int wave = t >> 6, lane = t & 63;
    const int l15 = lane & 15, lq = lane >> 4, koff = lq * 8;
    const int wn = wave * 32;

    // B pointers + first-fragment prefetch (lands during phase 1)
    const bf16* Bt = w1t + (long)r * 65536;
    const bf16* Bp[2];
#pragma unroll
    for (int j = 0; j < 2; ++j)
        Bp[j] = Bt + (long)(wn + j * 16 + l15) * 256 + koff;
    bf16x8 b0[2], b1[2];
#pragma unroll
    for (int j = 0; j < 2; ++j) b0[j] = *(const bf16x8*)(Bp[j]);

    // ---- phase 1: 8 rows per wave, headers preloaded ----
    {
        const int rbase = m0 + wave * 8;
        int i0s[8], i1s[8];
#pragma unroll
        for (int rr = 0; rr < 8; ++rr) {
            int dc = rbase + rr; if (dc >= kN) dc = kN - 1;
            int seg = dc * 4 + r;
            i0s[rr] = row_ptr[seg];
            i1s[rr] = row_ptr[seg + 1];
        }
#pragma unroll
        for (int rr = 0; rr < 8; ++rr) {
            int dc = rbase + rr; if (dc >= kN) dc = kN - 1;
            bf16x4 sv = ((const bf16x4*)(Pb + (long)dc * 256))[lane];
            f32x4 a = {(float)sv[0], (float)sv[1], (float)sv[2], (float)sv[3]};
            int i = i0s[rr], i1 = i1s[rr];
            for (; i + 1 < i1; i += 2) {
                int s0 = srcidx[i], s1 = srcidx[i + 1];
                bf16x4 v0 = ((const bf16x4*)(Pb + (long)s0 * 256))[lane];
                bf16x4 v1 = ((const bf16x4*)(Pb + (long)s1 * 256))[lane];
                a[0] += (float)v0[0] + (float)v1[0];
                a[1] += (float)v0[1] + (float)v1[1];
                a[2] += (float)v0[2] + (float)v1[2];
                a[3] += (float)v0[3] + (float)v1[3];
            }
            if (i < i1) {
                bf16x4 v0 = ((const bf16x4*)(Pb + (long)srcidx[i] * 256))[lane];
                a[0] += (float)v0[0]; a[1] += (float)v0[1];
                a[2] += (float)v0[2]; a[3] += (float)v0[3];
            }
            bf16x4 o = {(bf16)a[0], (bf16)a[1], (bf16)a[2], (bf16)a[3]};
            *(bf16x4*)&As[wave * 8 + rr][lane * 4] = o;
        }
    }
    __syncthreads();

    // ---- phase 2: MFMA from LDS, B double-buffered in regs ----
    const bf16* Ar[4];
#pragma unroll
    for (int i = 0; i < 4; ++i) Ar[i] = &As[i * 16 + l15][koff];

    f32x4 acc[4][2];
#pragma unroll
    for (int i = 0; i < 4; ++i)
#pragma unroll
        for (int j = 0; j < 2; ++j) acc[i][j] = (f32x4){0.f, 0.f, 0.f, 0.f};

#pragma unroll
    for (int kt = 0; kt < 256; kt += 32) {
        int kn = kt + 32; if (kn >= 256) kn = 0;
#pragma unroll
        for (int j = 0; j < 2; ++j) b1[j] = *(const bf16x8*)(Bp[j] + kn);
        bf16x8 a[4];
#pragma unroll
        for (int i = 0; i < 4; ++i) a[i] = *(const bf16x8*)(Ar[i] + kt);
#pragma unroll
        for (int i = 0; i < 4; ++i)
#pragma unroll
            for (int j = 0; j < 2; ++j)
                acc[i][j] = __builtin_amdgcn_mfma_f32_16x16x32_bf16(a[i], b0[j], acc[i][j], 0, 0, 0);
#pragma unroll
        for (int j = 0; j < 2; ++j) b0[j] = b1[j];
    }

    // ---- epilogue: store h1F (frag-linear) + fused stats ----
    const int cB = r * 256;
    float sv[2] = {0, 0}, qv[2] = {0, 0};
#pragma unroll
    for (int i = 0; i < 4; ++i) {
        int rowb = m0 + i * 16 + lq * 4;
#pragma unroll
        for (int rr = 0; rr < 4; ++rr) {
            int gm = rowb + rr;
            if (gm < kN) {
#pragma unroll
                for (int j = 0; j < 2; ++j) {
                    int gn = wn + j * 16 + l15;
                    bf16 bv = (bf16)acc[i][j][rr];
                    int kk = cB + gn;
                    h1F[fragA_idx(gm, kk, 32)] = bv;
                    float f = (float)bv;
                    sv[j] += f; qv[j] += f * f;
                }
            }
        }
    }
#pragma unroll
    for (int j = 0; j < 2; ++j) {
        float s = sv[j], q = qv[j];
        s += __shfl_xor(s, 16); s += __shfl_xor(s, 32);
        q += __shfl_xor(q, 16); q += __shfl_xor(q, 32);
        if (lq == 0) {
            int gn = cB + wn + j * 16 + l15;
            atomicAdd(&stats[gn], s);
            atomicAdd(&stats[1024 + gn], q);
        }
    }
}

// ---------------------------------------------------------------------------
// GEMM1 layer 1: A = a1b[r] [N,32] bf16 (K=32, one MFMA step) + fused stats.
// h1 written FRAG-LINEAR.
// ---------------------------------------------------------------------------
__global__ __launch_bounds__(512) void k_l1gemm(
    const bf16* __restrict__ a1b, const bf16* __restrict__ w1tL1,
    bf16* __restrict__ h1F, float* __restrict__ stats)
{
    const int t = threadIdx.x;
    const int r = blockIdx.y;
    const int m0 = blockIdx.x * 128;
    const int wave = t >> 6, lane = t & 63;
    const int l15 = lane & 15, lq = lane >> 4, koff = lq * 8;
    const int wm = (wave & 1) * 64, wn = (wave >> 1) * 64;

    bf16x8 a[4], b[4];
#pragma unroll
    for (int i = 0; i < 4; ++i) {
        int gm = m0 + wm + i * 16 + l15;
        if (gm >= kN) gm = kN - 1;
        a[i] = *(const bf16x8*)(a1b + ((long)r * kN + gm) * 32 + koff);
    }
#pragma unroll
    for (int j = 0; j < 4; ++j)
        b[j] = *(const bf16x8*)(w1tL1 + (long)r * 8192 + (long)(wn + j * 16 + l15) * 32 + koff);

    f32x4 acc[4][4];
#pragma unroll
    for (int i = 0; i < 4; ++i)
#pragma unroll
        for (int j = 0; j < 4; ++j)
            acc[i][j] = __builtin_amdgcn_mfma_f32_16x16x32_bf16(a[i], b[j],
                        (f32x4){0.f, 0.f, 0.f, 0.f}, 0, 0, 0);

    const int cB = r * 256;
    float sv[4] = {0,0,0,0}, qv[4] = {0,0,0,0};
#pragma unroll
    for (int i = 0; i < 4; ++i) {
        int rowb = m0 + wm + i * 16 + lq * 4;
#pragma unroll
        for (int rr = 0; rr < 4; ++rr) {
            int gm = rowb + rr;
            if (gm < kN) {
#pragma unroll
                for (int j = 0; j < 4; ++j) {
                    int gn = wn + j * 16 + l15;
                    bf16 bv = (bf16)acc[i][j][rr];
                    int kk = cB + gn;
                    h1F[fragA_idx(gm, kk, 32)] = bv;
                    float f = (float)bv;
                    sv[j] += f; qv[j] += f * f;
                }
            }
        }
    }
#pragma unroll
    for (int j = 0; j < 4; ++j) {
        float s = sv[j], q = qv[j];
        s += __shfl_xor(s, 16); s += __shfl_xor(s, 32);
        q += __shfl_xor(q, 16); q += __shfl_xor(q, 32);
        if (lq == 0) {
            int gn = cB + wn + j * 16 + l15;
            atomicAdd(&stats[gn], s);
            atomicAdd(&stats[1024 + gn], q);
        }
    }
}

// ---------------------------------------------------------------------------
// GEMM2 v7 (barrier-free, LDS-free): C = relu([A1 | max(h+u,0)] @ B' + bias).
// Diagnosis history: three barrier-coupled structures (v4/v5/v6) all idled at
// <8% on every pipe with occupancy pinned ~17-19%. v7 removes inter-wave
// coupling entirely: 256 thr = 4 INDEPENDENT waves, each owning a 64-row x
// 64-col output tile. No __syncthreads, no LDS.
//  * A2 (h1F) and A1F (xb1F) are FRAG-LINEAR: one 1KB contiguous load per
//    A-frag per wave. A1 (Pb, layers 2/3) stays row-major (gather needs it):
//    strided loads for only 8/40 ks.
//  * BN folded into weights: scl>0 (g=ones) => relu(h*scl+shf)@w2 =
//    max(h + u, 0) @ (scl*w2), u = shf/scl = bt/scl - mu. w2 packed scaled
//    AFTER bn_params (k_wt_fs, in-path, ~µs). Reader: add+max per element.
//  * 4 waves/block share the same 64-row A panel -> L1 de-dups the 4x reads.
//  * Rows >= M read garbage pad (never stored; MFMA rows independent).
// VGPR ~130 -> 3 blocks/CU; grid 782 -> whole grid resident, free-running.
// ---------------------------------------------------------------------------
template<int CHUNKS, int C1, bool A1F, bool PoolOut>
__global__ __launch_bounds__(256, 3) void k_gemm2(
    const bf16* __restrict__ A1,
    const bf16* __restrict__ A2F,
    const bf16* __restrict__ Bt,
    bf16* __restrict__ Cout,
    int M, const float* __restrict__ bias,
    const float* __restrict__ u,
    const int* __restrict__ batch, float* __restrict__ pooled)
{
    constexpr int KS  = CHUNKS * 4;   // total 32-wide k-steps
    constexpr int KS1 = C1 * 4;       // A1 k-steps
    constexpr int KS2 = KS - KS1;     // A2 k-steps (= 32 for all layers)
    static_assert(KS2 == 32, "h1F packed with KSR=32");

    const int t = threadIdx.x;
    const int wave = t >> 6, lane = t & 63;
    const int l15 = lane & 15, lq = lane >> 4, koff = lq * 8;
    const int cg = wave;              // col-group: cols [cg*64, cg*64+64)
    const int m0 = blockIdx.x * 64;
    const int mp = m0 >> 4;           // A-panel base (panels mp..mp+3)

    const bf16* Bp[4];
#pragma unroll
    for (int j = 0; j < 4; ++j)
        Bp[j] = Bt + ((long)(cg * 4 + j) * KS) * 512 + lane * 8;

    f32x4 acc[4][4];
#pragma unroll
    for (int i = 0; i < 4; ++i)
#pragma unroll
        for (int j = 0; j < 4; ++j) acc[i][j] = (f32x4){0.f, 0.f, 0.f, 0.f};

    // ---- phase 1: A1 part (no BN) ----
#pragma unroll
    for (int ks = 0; ks < KS1; ++ks) {
        bf16x8 a[4], b[4];
#pragma unroll
        for (int i = 0; i < 4; ++i) {
            if (A1F) {
                a[i] = *(const bf16x8*)(A1 + ((long)(mp + i) * KS1 + ks) * 512 + lane * 8);
            } else {
                int gm = m0 + i * 16 + l15; if (gm >= M) gm = M - 1;
                a[i] = *(const bf16x8*)(A1 + (long)gm * 256 + ks * 32 + koff);
            }
        }
#pragma unroll
        for (int j = 0; j < 4; ++j) b[j] = *(const bf16x8*)(Bp[j] + (long)ks * 512);
#pragma unroll
        for (int i = 0; i < 4; ++i)
#pragma unroll
            for (int j = 0; j < 4; ++j)
                acc[i][j] = __builtin_amdgcn_mfma_f32_16x16x32_bf16(a[i], b[j], acc[i][j], 0, 0, 0);
    }

    // ---- phase 2: A2 (h1F) with u-shift + relu ----
#pragma unroll 4
    for (int k2 = 0; k2 < KS2; ++k2) {
        float4 u0 = *(const float4*)(u + k2 * 32 + koff);
        float4 u1 = *(const float4*)(u + k2 * 32 + koff + 4);
        float u8[8] = {u0.x, u0.y, u0.z, u0.w, u1.x, u1.y, u1.z, u1.w};
        bf16x8 a[4], b[4];
#pragma unroll
        for (int i = 0; i < 4; ++i) {
            bf16x8 h = *(const bf16x8*)(A2F + ((long)(mp + i) * 32 + k2) * 512 + lane * 8);
            bf16x8 o;
#pragma unroll
            for (int e = 0; e < 8; ++e)
                o[e] = (bf16)fmaxf((float)h[e] + u8[e], 0.f);
            a[i] = o;
        }
#pragma unroll
        for (int j = 0; j < 4; ++j) b[j] = *(const bf16x8*)(Bp[j] + (long)(KS1 + k2) * 512);
#pragma unroll
        for (int i = 0; i < 4; ++i)
#pragma unroll
            for (int j = 0; j < 4; ++j)
                acc[i][j] = __builtin_amdgcn_mfma_f32_16x16x32_bf16(a[i], b[j], acc[i][j], 0, 0, 0);
    }

    // ---- epilogue ----
#pragma unroll
    for (int i = 0; i < 4; ++i) {
        int rowb = m0 + i * 16 + lq * 4;
#pragma unroll
        for (int rr = 0; rr < 4; ++rr) {
            int gm = rowb + rr;
            if (gm < M) {
                int g = PoolOut ? batch[gm] : 0;
#pragma unroll
                for (int j = 0; j < 4; ++j) {
                    int gn = cg * 64 + j * 16 + l15;
                    float v = fmaxf(acc[i][j][rr] + bias[gn], 0.f);
                    if (PoolOut) atomicAdd(&pooled[(long)g * 256 + gn], v);
                    else         Cout[(long)gm * 256 + gn] = (bf16)v;
                }
            }
        }
    }
}

// ---------------------------------------------------------------------------
// CSR build
__global__ void k_hist(const int* __restrict__ ei, const int* __restrict__ et,
                       int* __restrict__ hist)
{
    int e = blockIdx.x * 256 + threadIdx.x;
    if (e >= kE) return;
    atomicAdd(&hist[ei[kE + e] * 4 + et[e]], 1);
}

__global__ void k_scan1(const int* __restrict__ hist, int* __restrict__ bsum)
{
    __shared__ int sd[256];
    int i = blockIdx.x * 256 + threadIdx.x;
    sd[threadIdx.x] = (i < kSeg) ? hist[i] : 0;
    __syncthreads();
    for (int o = 128; o > 0; o >>= 1) {
        if (threadIdx.x < o) sd[threadIdx.x] += sd[threadIdx.x + o];
        __syncthreads();
    }
    if (threadIdx.x == 0) bsum[blockIdx.x] = sd[0];
}

__global__ __launch_bounds__(1024) void k_scan2(const int* __restrict__ bsum,
                                                int* __restrict__ boff)
{
    __shared__ int sd[1024];
    int t = threadIdx.x;
    sd[t] = (t < kScanB) ? bsum[t] : 0;
    __syncthreads();
    for (int o = 1; o < 1024; o <<= 1) {
        int v = (t >= o) ? sd[t - o] : 0;
        __syncthreads();
        sd[t] += v;
        __syncthreads();
    }
    if (t < kScanB) boff[t] = (t == 0) ? 0 : sd[t - 1];
}

__global__ void k_scan3(const int* __restrict__ hist, const int* __restrict__ boff,
                        int* __restrict__ row_ptr, int* __restrict__ cursor)
{
    __shared__ int sd[256];
    int i = blockIdx.x * 256 + threadIdx.x;
    int v = (i < kSeg) ? hist[i] : 0;
    sd[threadIdx.x] = v;
    __syncthreads();
    for (int o = 1; o < 256; o <<= 1) {
        int u = (threadIdx.x >= o) ? sd[threadIdx.x - o] : 0;
        __syncthreads();
        sd[threadIdx.x] += u;
        __syncthreads();
    }
    if (i <= kSeg) {
        int excl = boff[blockIdx.x] + sd[threadIdx.x] - v;
        row_ptr[i] = excl;
        if (i < kSeg) cursor[i] = excl;
    }
}

__global__ void k_fill(const int* __restrict__ ei, const int* __restrict__ et,
                       int* __restrict__ cursor, int* __restrict__ srcidx)
{
    int e = blockIdx.x * 256 + threadIdx.x;
    if (e >= kE) return;
    int key = ei[kE + e] * 4 + et[e];
    int pos = atomicAdd(&cursor[key], 1);
    srcidx[pos] = ei[e];
}

// ---------------------------------------------------------------------------
// layer-1 aggregate: a1b[r][d][ch] = bf16( x[d][ch] + sum_src x[src][ch] ), ch<11
__global__ void k_agg11(const float* __restrict__ x, const int* __restrict__ srcidx,
                        const int* __restrict__ row_ptr, bf16* __restrict__ a1b)
{
    long gid = (long)blockIdx.x * 256 + threadIdx.x;
    if (gid >= (long)kSeg * 32) return;
    int ch  = (int)(gid & 31);
    int seg = (int)(gid >> 5);
    int d = seg >> 2, r = seg & 3;
    float acc = 0.f;
    if (ch < 11) {
        acc = x[(long)d * 11 + ch];
        int i0 = row_ptr[seg], i1 = row_ptr[seg + 1];
        for (int i = i0; i < i1; ++i) acc += x[(long)srcidx[i] * 11 + ch];
    }
    a1b[((long)r * kN + d) * 32 + ch] = (bf16)acc;
}

// x [N,11] fp32 -> xb1F frag-linear (KSR=4), k=11..127 zero-padded
__global__ void k_xpad(const float* __restrict__ x, bf16* __restrict__ xb1F)
{
    long gid = (long)blockIdx.x * 256 + threadIdx.x;
    if (gid >= (long)kN * 128) return;
    int c = (int)(gid & 127); int d = (int)(gid >> 7);
    long idx = ((long)(d >> 4) * 4 + (c >> 5)) * 512
             + ((c >> 3) & 3) * 128 + (d & 15) * 8 + (c & 7);
    xb1F[idx] = (c < 11) ? (bf16)x[(long)d * 11 + c] : (bf16)0.f;
}

// weight transpose-pack: in [K,N] fp32 -> out[n*ldout + coff + k] bf16
// (still used for w1t consumed by k_rgin1's strided reg loads)
__global__ void k_wt_s(const float* __restrict__ in, bf16* __restrict__ out,
                       int K, int N, int ldout, int coff)
{
    int i = blockIdx.x * 256 + threadIdx.x;
    if (i >= K * N) return;
    int n = i / K, k = i - n * K;
    out[(long)n * ldout + coff + k] = (bf16)in[(long)k * N + n];
}

// fragment-linear B pack: element (n,k) -> blk*512 + lq*128 + l15*8 + u,
// blk = ((n>>6)*4 + ((n>>4)&3))*KS + (k>>5).
__global__ void k_wt_f(const float* __restrict__ in, bf16* __restrict__ out,
                       int Kin, int k0, int KS)
{
    int i = blockIdx.x * 256 + threadIdx.x;
    if (i >= Kin * 256) return;
    int n = i & 255, krel = i >> 8;
    int k = k0 + krel;
    int blk = ((n >> 6) * 4 + ((n >> 4) & 3)) * KS + (k >> 5);
    int idx = blk * 512 + ((k >> 3) & 3) * 128 + (n & 15) * 8 + (k & 7);
    out[idx] = (bf16)in[(long)krel * 256 + n];
}

// scaled fragment-linear B pack: out = bf16( in[krel][n] * s[krel] )  (w2' = scl*w2)
__global__ void k_wt_fs(const float* __restrict__ in, const float* __restrict__ s,
                        bf16* __restrict__ out, int Kin, int k0, int KS)
{
    int i = blockIdx.x * 256 + threadIdx.x;
    if (i >= Kin * 256) return;
    int n = i & 255, krel = i >> 8;
    int k = k0 + krel;
    int blk = ((n >> 6) * 4 + ((n >> 4) & 3)) * KS + (k >> 5);
    int idx = blk * 512 + ((k >> 3) & 3) * 128 + (n & 15) * 8 + (k & 7);
    out[idx] = (bf16)(in[(long)krel * 256 + n] * s[krel]);
}

// layer-1 w1 pack: [4][11][256] fp32 -> [4][256][32] bf16 zero-padded
__global__ void k_wtL1(const float* __restrict__ w1, bf16* __restrict__ out)
{
    int i = blockIdx.x * 256 + threadIdx.x;
    if (i >= 4 * 256 * 32) return;
    int r = i >> 13, rem = i & 8191, n = rem >> 5, k = rem & 31;
    out[i] = (k < 11) ? (bf16)w1[(long)r * 11 * 256 + (long)k * 256 + n] : (bf16)0.f;
}

// BN params: scl = g*rsqrt(var+eps) (>0 since g=ones); u = bt/scl - mu so that
// relu(h*scl+shf) = scl*max(h+u,0), folding scl into w2 (k_wt_fs).
__global__ void k_bn_params(const float* __restrict__ stats,
                            const float* __restrict__ g, const float* __restrict__ bt,
                            float* __restrict__ scl, float* __restrict__ uu)
{
    int c = blockIdx.x * 256 + threadIdx.x;  // < 1024
    const float invN = 1.0f / (float)kN;
    float mu  = stats[c] * invN;
    float var = stats[1024 + c] * invN - mu * mu;
    float sc  = g[c] * rsqrtf(var + 1e-5f);
    scl[c] = sc;
    uu[c]  = bt[c] / sc - mu;
}

__global__ void k_bias_total(const float* sb0, const float* b20,
                             const float* sb1, const float* b21,
                             const float* sb2, const float* b22,
                             float* __restrict__ btt)
{
    int l = blockIdx.x, j = threadIdx.x;
    const float* sb = (l == 0) ? sb0 : (l == 1) ? sb1 : sb2;
    const float* b2 = (l == 0) ? b20 : (l == 1) ? b21 : b22;
    float v = sb[j];
#pragma unroll
    for (int r = 0; r < 4; ++r) v += b2[r * 256 + j];
    btt[l * 256 + j] = v;
}

__global__ void k_counts(const int* __restrict__ batch, float* __restrict__ counts)
{
    int v = blockIdx.x * 256 + threadIdx.x;
    if (v < kN) atomicAdd(&counts[batch[v]], 1.0f);
}

__global__ __launch_bounds__(64) void k_head(const float* __restrict__ pooled,
                                             const float* __restrict__ counts,
                                             const float* __restrict__ lw,
                                             const float* __restrict__ lb,
                                             float* __restrict__ out)
{
    int g = blockIdx.x;
    int l = threadIdx.x;
    float inv = 1.0f / fmaxf(counts[g], 1.0f);
    float acc[kT];
#pragma unroll
    for (int t = 0; t < kT; ++t) acc[t] = 0.f;
    for (int k = l; k < 256; k += 64) {
        float p = pooled[((long)g << 8) + k] * inv;
#pragma unroll
        for (int t = 0; t < kT; ++t) acc[t] = fmaf(p, lw[k * kT + t], acc[t]);
    }
#pragma unroll
    for (int off = 32; off > 0; off >>= 1)
#pragma unroll
        for (int t = 0; t < kT; ++t) acc[t] += __shfl_down(acc[t], off);
    if (l == 0) {
#pragma unroll
        for (int t = 0; t < kT; ++t) out[(long)g * kT + t] = acc[t] + lb[t];
    }
}

// ---------------------------------------------------------------------------
extern "C" void kernel_launch(void* const* d_in, const int* in_sizes, int n_in,
                              void* d_out, int out_size, void* d_ws, size_t ws_size,
                              hipStream_t stream)
{
    const float* x     = (const float*)d_in[0];
    const int*   ei    = (const int*)d_in[1];
    const int*   et    = (const int*)d_in[2];
    const int*   batch = (const int*)d_in[3];

    const float *sw[3], *sb[3], *w1[3], *gmm[3], *btm[3], *w2[3], *b2[3];
    for (int l = 0; l < 3; ++l) {
        int b = 4 + l * 8;
        sw[l]  = (const float*)d_in[b + 0];
        sb[l]  = (const float*)d_in[b + 1];
        w1[l]  = (const float*)d_in[b + 2];
        // b+3 = b1 (cancels inside BatchNorm)
        gmm[l] = (const float*)d_in[b + 4];
        btm[l] = (const float*)d_in[b + 5];
        w2[l]  = (const float*)d_in[b + 6];
        b2[l]  = (const float*)d_in[b + 7];
    }
    const float* lin_w = (const float*)d_in[28];
    const float* lin_b = (const float*)d_in[29];
    float* out = (float*)d_out;
    (void)in_sizes; (void)n_in; (void)out_size;

    // ---- workspace (~190 MB) ----
    const int kPanels = 3128;  // ceil(50048/16): covers reader's mp+3 overrun
    char* wsb = (char*)d_ws;
    size_t off = 0;
    auto alloc = [&](size_t bytes) { void* p = wsb + off; off = (off + bytes + 255) & ~(size_t)255; return p; };
    bf16*  Pb0    = (bf16*) alloc((size_t)kN * 256 * 2);
    bf16*  Pb1    = (bf16*) alloc((size_t)kN * 256 * 2);
    bf16*  h1F    = (bf16*) alloc((size_t)kPanels * 32 * 512 * 2);  // frag-linear
    bf16*  a1b    = (bf16*) alloc((size_t)4 * kN * 32 * 2);
    bf16*  xb1F   = (bf16*) alloc((size_t)kPanels * 4 * 512 * 2);   // frag-linear
    bf16*  w1t    = (bf16*) alloc((size_t)2 * 4 * 65536 * 2);   // layers 2,3
    bf16*  w1tL1  = (bf16*) alloc((size_t)4 * 256 * 32 * 2);
    bf16*  Bc0    = (bf16*) alloc((size_t)256 * 1152 * 2);      // frag-linear [sw_pad128 | w2']
    bf16*  Bc1    = (bf16*) alloc((size_t)256 * 1280 * 2);
    bf16*  Bc2    = (bf16*) alloc((size_t)256 * 1280 * 2);
    int*   hist   = (int*)  alloc((size_t)(kSeg + 1) * 4);
    int*   row_ptr= (int*)  alloc((size_t)(kSeg + 1) * 4);
    int*   cursor = (int*)  alloc((size_t)kSeg * 4);
    int*   srcidx = (int*)  alloc((size_t)kE * 4);
    int*   bsum   = (int*)  alloc((size_t)kScanB * 4);
    int*   boff   = (int*)  alloc((size_t)kScanB * 4);
    float* stats  = (float*)alloc(2048 * 4);
    float* scl    = (float*)alloc(1024 * 4);
    float* uu     = (float*)alloc(1024 * 4);
    float* btt    = (float*)alloc(3 * 256 * 4);
    float* pooled = (float*)alloc((size_t)kG * 256 * 4);
    float* counts = (float*)alloc(kG * 4);
    if (ws_size < off) return;  // clean absmax-fail instead of OOB crash

    const dim3 gL1((kN + 127) / 128, 4);  // l1 GEMM grid (512 thr)
    const dim3 gR((kN + 63) / 64, 4);     // rgin grid (512 thr, M-tile 64)
    const dim3 g2((kN + 63) / 64);        // GEMM2 grid (256 thr, 4 indep waves)

    // ---- CSR build (parallel scan) + weight prepack ----
    hipMemsetAsync(hist, 0, (size_t)(kSeg + 1) * 4, stream);
    k_hist<<<(kE + 255) / 256, 256, 0, stream>>>(ei, et, hist);
    k_scan1<<<kScanB, 256, 0, stream>>>(hist, bsum);
    k_scan2<<<1, 1024, 0, stream>>>(bsum, boff);
    k_scan3<<<kScanB, 256, 0, stream>>>(hist, boff, row_ptr, cursor);
    k_fill<<<(kE + 255) / 256, 256, 0, stream>>>(ei, et, cursor, srcidx);

    k_bias_total<<<3, 256, 0, stream>>>(sb[0], b2[0], sb[1], b2[1], sb[2], b2[2], btt);
    k_xpad<<<(int)(((long)kN * 128 + 255) / 256), 256, 0, stream>>>(x, xb1F);
    k_wtL1<<<(4 * 256 * 32 + 255) / 256, 256, 0, stream>>>(w1[0], w1tL1);
    for (int l = 1; l < 3; ++l)
        for (int r = 0; r < 4; ++r)
            k_wt_s<<<256, 256, 0, stream>>>(w1[l] + (long)r * 65536,
                                            w1t + (long)(l - 1) * 4 * 65536 + (long)r * 65536,
                                            256, 256, 256, 0);
    // frag-linear B packs, sw (unscaled) parts only; w2' packed in-path after stats
    hipMemsetAsync(Bc0, 0, (size_t)256 * 1152 * 2, stream);
    k_wt_f<<<(11 * 256 + 255) / 256, 256, 0, stream>>>(sw[0], Bc0, 11, 0, 36);
    k_wt_f<<<256, 256, 0, stream>>>(sw[1], Bc1, 256, 0, 40);
    k_wt_f<<<256, 256, 0, stream>>>(sw[2], Bc2, 256, 0, 40);

    k_counts<<<(kN + 255) / 256, 256, 0, stream>>>(batch, counts);  // counts poisoned -> must init
    hipMemsetAsync(pooled, 0, (size_t)kG * 256 * 4, stream);

    // ---------------- layer 1 ----------------
    k_agg11<<<(int)(((long)kSeg * 32 + 255) / 256), 256, 0, stream>>>(x, srcidx, row_ptr, a1b);
    hipMemsetAsync(stats, 0, 2048 * 4, stream);
    k_l1gemm<<<gL1, 512, 0, stream>>>(a1b, w1tL1, h1F, stats);
    k_bn_params<<<4, 256, 0, stream>>>(stats, gmm[0], btm[0], scl, uu);
    k_wt_fs<<<1024, 256, 0, stream>>>(w2[0], scl, Bc0, 1024, 128, 36);
    k_gemm2<9, 1, true, false><<<g2, 256, 0, stream>>>(xb1F, h1F, Bc0,
                                                       Pb0, kN, btt + 0, uu, nullptr, nullptr);

    // ---------------- layer 2 ----------------
    hipMemsetAsync(stats, 0, 2048 * 4, stream);
    k_rgin1<<<gR, 512, 0, stream>>>(Pb0, srcidx, row_ptr, w1t, h1F, stats);
    k_bn_params<<<4, 256, 0, stream>>>(stats, gmm[1], btm[1], scl, uu);
    k_wt_fs<<<1024, 256, 0, stream>>>(w2[1], scl, Bc1, 1024, 256, 40);
    k_gemm2<10, 2, false, false><<<g2, 256, 0, stream>>>(Pb0, h1F, Bc1,
                                                         Pb1, kN, btt + 256, uu, nullptr, nullptr);

    // ---------------- layer 3 (pool fused into GEMM2) ----------------
    hipMemsetAsync(stats, 0, 2048 * 4, stream);
    k_rgin1<<<gR, 512, 0, stream>>>(Pb1, srcidx, row_ptr, w1t + (size_t)4 * 65536, h1F, stats);
    k_bn_params<<<4, 256, 0, stream>>>(stats, gmm[2], btm[2], scl, uu);
    k_wt_fs<<<1024, 256, 0, stream>>>(w2[2], scl, Bc2, 1024, 256, 40);
    k_gemm2<10, 2, false, true><<<g2, 256, 0, stream>>>(Pb1, h1F, Bc2,
                                                        nullptr, kN, btt + 512, uu, batch, pooled);

    // ---------------- head ----------------
    k_head<<<kG, 64, 0, stream>>>(pooled, counts, lin_w, lin_b, out);
}

// Round 6
// 1025.867 us; speedup vs baseline: 1.0930x; 1.0930x over previous
//
#include <hip/hip_runtime.h>

static const int kN = 50000;   // nodes
static const int kE = 300000;  // edges
static const int kG = 2048;    // graphs
static const int kT = 19;      // targets
static const int kSeg = kN * 4;  // CSR segments: key = dst*4 + rel
static const int kScanB = (kSeg + 256) / 256;  // 784 blocks covers kSeg+1

typedef __bf16 bf16;
typedef __bf16 bf16x8 __attribute__((ext_vector_type(8)));
typedef __bf16 bf16x4 __attribute__((ext_vector_type(4)));
typedef float  f32x4  __attribute__((ext_vector_type(4)));

// Fragment-linear element index for an A-operand matrix: element (row,k) ->
// ((row>>4)*KSR + (k>>5))*512 + ((k>>3)&3)*128 + (row&15)*8 + (k&7).
// One (panel,ks) block = 512 elements = 1 KB contiguous.
__device__ __forceinline__ long fragA_idx(int row, int k, int KSR) {
    return ((long)(row >> 4) * KSR + (k >> 5)) * 512
         + ((k >> 3) & 3) * 128 + (row & 15) * 8 + (k & 7);
}

// direct-to-LDS 16B/lane DMA: dest = ldsbase + lane*16 (linear), src per-lane.
#define GLOAD_LDS16(GP, LP) __builtin_amdgcn_global_load_lds(                 \
    (const __attribute__((address_space(1))) unsigned int*)(GP),              \
    (__attribute__((address_space(3))) unsigned int*)(LP), 16, 0, 0)

// ---------------------------------------------------------------------------
// GEMM1 layers 2/3: aggregate (CSR, +self) into LDS, then MFMA vs w1t[r].
// Grid (ceil(N/64), 4=rel), 512 threads (8 waves). h1 written FRAG-LINEAR.
// ---------------------------------------------------------------------------
__global__ __launch_bounds__(512) void k_rgin1(
    const bf16* __restrict__ Pb, const int* __restrict__ srcidx,
    const int* __restrict__ row_ptr, const bf16* __restrict__ w1t,
    bf16* __restrict__ h1F, float* __restrict__ stats)
{
    __shared__ bf16 As[64][264];   // row stride 264 bf16 = 132 dwords
    const int t = threadIdx.x;
    const int r = blockIdx.y;
    const int m0 = blockIdx.x * 64;
    const int wave = t >> 6, lane = t & 63;
    const int l15 = lane & 15, lq = lane >> 4, koff = lq * 8;
    const int wn = wave * 32;

    // B pointers + first-fragment prefetch (lands during phase 1)
    const bf16* Bt = w1t + (long)r * 65536;
    const bf16* Bp[2];
#pragma unroll
    for (int j = 0; j < 2; ++j)
        Bp[j] = Bt + (long)(wn + j * 16 + l15) * 256 + koff;
    bf16x8 b0[2], b1[2];
#pragma unroll
    for (int j = 0; j < 2; ++j) b0[j] = *(const bf16x8*)(Bp[j]);

    // ---- phase 1: 8 rows per wave, headers preloaded ----
    {
        const int rbase = m0 + wave * 8;
        int i0s[8], i1s[8];
#pragma unroll
        for (int rr = 0; rr < 8; ++rr) {
            int dc = rbase + rr; if (dc >= kN) dc = kN - 1;
            int seg = dc * 4 + r;
            i0s[rr] = row_ptr[seg];
            i1s[rr] = row_ptr[seg + 1];
        }
#pragma unroll
        for (int rr = 0; rr < 8; ++rr) {
            int dc = rbase + rr; if (dc >= kN) dc = kN - 1;
            bf16x4 sv = ((const bf16x4*)(Pb + (long)dc * 256))[lane];
            f32x4 a = {(float)sv[0], (float)sv[1], (float)sv[2], (float)sv[3]};
            int i = i0s[rr], i1 = i1s[rr];
            for (; i + 1 < i1; i += 2) {
                int s0 = srcidx[i], s1 = srcidx[i + 1];
                bf16x4 v0 = ((const bf16x4*)(Pb + (long)s0 * 256))[lane];
                bf16x4 v1 = ((const bf16x4*)(Pb + (long)s1 * 256))[lane];
                a[0] += (float)v0[0] + (float)v1[0];
                a[1] += (float)v0[1] + (float)v1[1];
                a[2] += (float)v0[2] + (float)v1[2];
                a[3] += (float)v0[3] + (float)v1[3];
            }
            if (i < i1) {
                bf16x4 v0 = ((const bf16x4*)(Pb + (long)srcidx[i] * 256))[lane];
                a[0] += (float)v0[0]; a[1] += (float)v0[1];
                a[2] += (float)v0[2]; a[3] += (float)v0[3];
            }
            bf16x4 o = {(bf16)a[0], (bf16)a[1], (bf16)a[2], (bf16)a[3]};
            *(bf16x4*)&As[wave * 8 + rr][lane * 4] = o;
        }
    }
    __syncthreads();

    // ---- phase 2: MFMA from LDS, B double-buffered in regs ----
    const bf16* Ar[4];
#pragma unroll
    for (int i = 0; i < 4; ++i) Ar[i] = &As[i * 16 + l15][koff];

    f32x4 acc[4][2];
#pragma unroll
    for (int i = 0; i < 4; ++i)
#pragma unroll
        for (int j = 0; j < 2; ++j) acc[i][j] = (f32x4){0.f, 0.f, 0.f, 0.f};

#pragma unroll
    for (int kt = 0; kt < 256; kt += 32) {
        int kn = kt + 32; if (kn >= 256) kn = 0;
#pragma unroll
        for (int j = 0; j < 2; ++j) b1[j] = *(const bf16x8*)(Bp[j] + kn);
        bf16x8 a[4];
#pragma unroll
        for (int i = 0; i < 4; ++i) a[i] = *(const bf16x8*)(Ar[i] + kt);
#pragma unroll
        for (int i = 0; i < 4; ++i)
#pragma unroll
            for (int j = 0; j < 2; ++j)
                acc[i][j] = __builtin_amdgcn_mfma_f32_16x16x32_bf16(a[i], b0[j], acc[i][j], 0, 0, 0);
#pragma unroll
        for (int j = 0; j < 2; ++j) b0[j] = b1[j];
    }

    // ---- epilogue: store h1F (frag-linear) + fused stats ----
    const int cB = r * 256;
    float sv[2] = {0, 0}, qv[2] = {0, 0};
#pragma unroll
    for (int i = 0; i < 4; ++i) {
        int rowb = m0 + i * 16 + lq * 4;
#pragma unroll
        for (int rr = 0; rr < 4; ++rr) {
            int gm = rowb + rr;
            if (gm < kN) {
#pragma unroll
                for (int j = 0; j < 2; ++j) {
                    int gn = wn + j * 16 + l15;
                    bf16 bv = (bf16)acc[i][j][rr];
                    int kk = cB + gn;
                    h1F[fragA_idx(gm, kk, 32)] = bv;
                    float f = (float)bv;
                    sv[j] += f; qv[j] += f * f;
                }
            }
        }
    }
#pragma unroll
    for (int j = 0; j < 2; ++j) {
        float s = sv[j], q = qv[j];
        s += __shfl_xor(s, 16); s += __shfl_xor(s, 32);
        q += __shfl_xor(q, 16); q += __shfl_xor(q, 32);
        if (lq == 0) {
            int gn = cB + wn + j * 16 + l15;
            atomicAdd(&stats[gn], s);
            atomicAdd(&stats[1024 + gn], q);
        }
    }
}

// ---------------------------------------------------------------------------
// GEMM1 layer 1: A = a1b[r] [N,32] bf16 (K=32, one MFMA step) + fused stats.
// h1 written FRAG-LINEAR.
// ---------------------------------------------------------------------------
__global__ __launch_bounds__(512) void k_l1gemm(
    const bf16* __restrict__ a1b, const bf16* __restrict__ w1tL1,
    bf16* __restrict__ h1F, float* __restrict__ stats)
{
    const int t = threadIdx.x;
    const int r = blockIdx.y;
    const int m0 = blockIdx.x * 128;
    const int wave = t >> 6, lane = t & 63;
    const int l15 = lane & 15, lq = lane >> 4, koff = lq * 8;
    const int wm = (wave & 1) * 64, wn = (wave >> 1) * 64;

    bf16x8 a[4], b[4];
#pragma unroll
    for (int i = 0; i < 4; ++i) {
        int gm = m0 + wm + i * 16 + l15;
        if (gm >= kN) gm = kN - 1;
        a[i] = *(const bf16x8*)(a1b + ((long)r * kN + gm) * 32 + koff);
    }
#pragma unroll
    for (int j = 0; j < 4; ++j)
        b[j] = *(const bf16x8*)(w1tL1 + (long)r * 8192 + (long)(wn + j * 16 + l15) * 32 + koff);

    f32x4 acc[4][4];
#pragma unroll
    for (int i = 0; i < 4; ++i)
#pragma unroll
        for (int j = 0; j < 4; ++j)
            acc[i][j] = __builtin_amdgcn_mfma_f32_16x16x32_bf16(a[i], b[j],
                        (f32x4){0.f, 0.f, 0.f, 0.f}, 0, 0, 0);

    const int cB = r * 256;
    float sv[4] = {0,0,0,0}, qv[4] = {0,0,0,0};
#pragma unroll
    for (int i = 0; i < 4; ++i) {
        int rowb = m0 + wm + i * 16 + lq * 4;
#pragma unroll
        for (int rr = 0; rr < 4; ++rr) {
            int gm = rowb + rr;
            if (gm < kN) {
#pragma unroll
                for (int j = 0; j < 4; ++j) {
                    int gn = wn + j * 16 + l15;
                    bf16 bv = (bf16)acc[i][j][rr];
                    int kk = cB + gn;
                    h1F[fragA_idx(gm, kk, 32)] = bv;
                    float f = (float)bv;
                    sv[j] += f; qv[j] += f * f;
                }
            }
        }
    }
#pragma unroll
    for (int j = 0; j < 4; ++j) {
        float s = sv[j], q = qv[j];
        s += __shfl_xor(s, 16); s += __shfl_xor(s, 32);
        q += __shfl_xor(q, 16); q += __shfl_xor(q, 32);
        if (lq == 0) {
            int gn = cB + wn + j * 16 + l15;
            atomicAdd(&stats[gn], s);
            atomicAdd(&stats[1024 + gn], q);
        }
    }
}

// ---------------------------------------------------------------------------
// GEMM2 v8 (m97-mold): C = relu([A1 | max(h+u,0)] @ B' + bias).
// Diagnosis: v4-v7 all bottlenecked on per-wave in-flight memory depth
// (registers can't hold a deep pipeline; 84-150 VGPR => ~2 loads in flight
// => Little's law caps at ~600 GB/s). v8 stages A via global_load_lds:
// in-flight bytes live in the vmcnt queue + LDS, costing ZERO VGPRs
// (m97: this structure = 874 TF on this chip).
//  * 128x128 tile: grid (391, 2 col-halves), 256 thr, wave = 64x64 quadrant.
//  * per ks (BK=32): stage ks+1 A-slab (8 x 1KB global_load_lds, 2/wave,
//    linear LDS dest); 4x ds_read_b128 A-frags from LDS (+BN add/relu VALU
//    for the h1F region); B frag-linear from L2, depth-2 reg prefetch;
//    16 MFMA; one __syncthreads (its vmcnt drain completes the staging).
//  * A-sources frag-linear (h1F KSR=32, xb1F KSR=4) -> 1KB contiguous
//    bursts; layers 2/3 A1=Pb row-major prefix (8/40 ks) uses per-lane
//    scattered global source (dest stays linear - rule m104 satisfied).
// LDS 16.4 KB; VGPR ~130 -> ~3 blocks/CU, ~8KB staged/block in flight.
// ---------------------------------------------------------------------------
template<int KS, int KS1, bool A1ROW, bool PoolOut>
__global__ __launch_bounds__(256) void k_gemm2(
    const bf16* __restrict__ A1F,   // A1ROW ? row-major [M,256] : frag-linear KSR=KS1
    const bf16* __restrict__ A2F,   // frag-linear KSR=32 (h1F)
    const bf16* __restrict__ Bt,    // frag-linear weights
    bf16* __restrict__ Cout,
    int M, const float* __restrict__ bias,
    const float* __restrict__ u,
    const int* __restrict__ batch, float* __restrict__ pooled)
{
    __shared__ __attribute__((aligned(16))) bf16 As[2][8][512];
    const int t = threadIdx.x;
    const int wave = t >> 6, lane = t & 63;
    const int l15 = lane & 15, lq = lane >> 4, koff = lq * 8;
    const int wr = wave & 1, wc = wave >> 1;
    const int wr4 = wr * 4;
    const int cy = blockIdx.y;
    const int m0 = blockIdx.x * 128;
    const int pbase = blockIdx.x * 8;
    const int nb = cy * 128 + wc * 64;   // wave col base
    const int g = cy * 2 + wc;           // frag-linear B col-group

    const bf16* Bp[4];
#pragma unroll
    for (int j = 0; j < 4; ++j)
        Bp[j] = Bt + ((long)(g * 4 + j) * KS) * 512 + lane * 8;

    f32x4 acc[4][4];
#pragma unroll
    for (int i = 0; i < 4; ++i)
#pragma unroll
        for (int j = 0; j < 4; ++j) acc[i][j] = (f32x4){0.f, 0.f, 0.f, 0.f};

    // stage one 32-wide k-slab (8 panels x 1KB); this wave does 2 chunks
    auto stage = [&](int ks, int buf) {
#pragma unroll
        for (int c = 0; c < 2; ++c) {
            const int chunk = wave + c * 4;
            const bf16* gp;
            if (A1ROW && ks < KS1) {
                int row = (pbase + chunk) * 16 + l15;
                if (row >= M) row = M - 1;
                gp = A1F + (long)row * 256 + ks * 32 + koff;   // scattered src
            } else if (ks < KS1) {
                gp = A1F + ((long)(pbase + chunk) * KS1 + ks) * 512 + lane * 8;
            } else {
                gp = A2F + ((long)(pbase + chunk) * 32 + (ks - KS1)) * 512 + lane * 8;
            }
            GLOAD_LDS16(gp, &As[buf][chunk][0]);
        }
    };

#define G2_STEP(KSI, BREG) do {                                               \
    const int buf_ = (KSI) & 1;                                               \
    if ((KSI) + 1 < KS) stage((KSI) + 1, buf_ ^ 1);                           \
    bf16x8 a_[4];                                                             \
    _Pragma("unroll")                                                         \
    for (int i_ = 0; i_ < 4; ++i_)                                            \
        a_[i_] = *(const bf16x8*)&As[buf_][wr4 + i_][lane * 8];               \
    if ((KSI) >= KS1) {                                                       \
        const int k2_ = (KSI) - KS1;                                          \
        float4 u0_ = *(const float4*)(u + k2_ * 32 + koff);                   \
        float4 u1_ = *(const float4*)(u + k2_ * 32 + koff + 4);               \
        float uv_[8] = {u0_.x, u0_.y, u0_.z, u0_.w,                           \
                        u1_.x, u1_.y, u1_.z, u1_.w};                          \
        _Pragma("unroll")                                                     \
        for (int i_ = 0; i_ < 4; ++i_) {                                      \
            bf16x8 h_ = a_[i_]; bf16x8 o_;                                    \
            _Pragma("unroll")                                                 \
            for (int e_ = 0; e_ < 8; ++e_)                                    \
                o_[e_] = (bf16)fmaxf((float)h_[e_] + uv_[e_], 0.f);           \
            a_[i_] = o_;                                                      \
        }                                                                     \
    }                                                                         \
    bf16x8 bu_[4];                                                            \
    _Pragma("unroll")                                                         \
    for (int j_ = 0; j_ < 4; ++j_) bu_[j_] = BREG[j_];                        \
    int nk_ = (KSI) + 2; if (nk_ >= KS) nk_ = 0;                              \
    _Pragma("unroll")                                                         \
    for (int j_ = 0; j_ < 4; ++j_)                                            \
        BREG[j_] = *(const bf16x8*)(Bp[j_] + (long)nk_ * 512);                \
    _Pragma("unroll")                                                         \
    for (int i_ = 0; i_ < 4; ++i_)                                            \
        _Pragma("unroll")                                                     \
        for (int j_ = 0; j_ < 4; ++j_)                                        \
            acc[i_][j_] = __builtin_amdgcn_mfma_f32_16x16x32_bf16(            \
                a_[i_], bu_[j_], acc[i_][j_], 0, 0, 0);                       \
    __syncthreads();                                                          \
} while (0)

    // prologue: B depth-2 prefetch + stage ks=0; barrier drains the DMA
    bf16x8 breg0[4], breg1[4];
#pragma unroll
    for (int j = 0; j < 4; ++j) breg0[j] = *(const bf16x8*)(Bp[j]);
#pragma unroll
    for (int j = 0; j < 4; ++j) breg1[j] = *(const bf16x8*)(Bp[j] + 512);
    stage(0, 0);
    __syncthreads();

    for (int ks = 0; ks < KS; ks += 2) {
        G2_STEP(ks,     breg0);
        G2_STEP(ks + 1, breg1);
    }
#undef G2_STEP

    // ---- epilogue ----
#pragma unroll
    for (int i = 0; i < 4; ++i) {
        int rowb = m0 + wr * 64 + i * 16 + lq * 4;
#pragma unroll
        for (int rr = 0; rr < 4; ++rr) {
            int gm = rowb + rr;
            if (gm < M) {
                int gg = PoolOut ? batch[gm] : 0;
#pragma unroll
                for (int j = 0; j < 4; ++j) {
                    int gn = nb + j * 16 + l15;
                    float v = fmaxf(acc[i][j][rr] + bias[gn], 0.f);
                    if (PoolOut) atomicAdd(&pooled[(long)gg * 256 + gn], v);
                    else         Cout[(long)gm * 256 + gn] = (bf16)v;
                }
            }
        }
    }
}

// ---------------------------------------------------------------------------
// CSR build
__global__ void k_hist(const int* __restrict__ ei, const int* __restrict__ et,
                       int* __restrict__ hist)
{
    int e = blockIdx.x * 256 + threadIdx.x;
    if (e >= kE) return;
    atomicAdd(&hist[ei[kE + e] * 4 + et[e]], 1);
}

__global__ void k_scan1(const int* __restrict__ hist, int* __restrict__ bsum)
{
    __shared__ int sd[256];
    int i = blockIdx.x * 256 + threadIdx.x;
    sd[threadIdx.x] = (i < kSeg) ? hist[i] : 0;
    __syncthreads();
    for (int o = 128; o > 0; o >>= 1) {
        if (threadIdx.x < o) sd[threadIdx.x] += sd[threadIdx.x + o];
        __syncthreads();
    }
    if (threadIdx.x == 0) bsum[blockIdx.x] = sd[0];
}

__global__ __launch_bounds__(1024) void k_scan2(const int* __restrict__ bsum,
                                                int* __restrict__ boff)
{
    __shared__ int sd[1024];
    int t = threadIdx.x;
    sd[t] = (t < kScanB) ? bsum[t] : 0;
    __syncthreads();
    for (int o = 1; o < 1024; o <<= 1) {
        int v = (t >= o) ? sd[t - o] : 0;
        __syncthreads();
        sd[t] += v;
        __syncthreads();
    }
    if (t < kScanB) boff[t] = (t == 0) ? 0 : sd[t - 1];
}

__global__ void k_scan3(const int* __restrict__ hist, const int* __restrict__ boff,
                        int* __restrict__ row_ptr, int* __restrict__ cursor)
{
    __shared__ int sd[256];
    int i = blockIdx.x * 256 + threadIdx.x;
    int v = (i < kSeg) ? hist[i] : 0;
    sd[threadIdx.x] = v;
    __syncthreads();
    for (int o = 1; o < 256; o <<= 1) {
        int u = (threadIdx.x >= o) ? sd[threadIdx.x - o] : 0;
        __syncthreads();
        sd[threadIdx.x] += u;
        __syncthreads();
    }
    if (i <= kSeg) {
        int excl = boff[blockIdx.x] + sd[threadIdx.x] - v;
        row_ptr[i] = excl;
        if (i < kSeg) cursor[i] = excl;
    }
}

__global__ void k_fill(const int* __restrict__ ei, const int* __restrict__ et,
                       int* __restrict__ cursor, int* __restrict__ srcidx)
{
    int e = blockIdx.x * 256 + threadIdx.x;
    if (e >= kE) return;
    int key = ei[kE + e] * 4 + et[e];
    int pos = atomicAdd(&cursor[key], 1);
    srcidx[pos] = ei[e];
}

// ---------------------------------------------------------------------------
// layer-1 aggregate: a1b[r][d][ch] = bf16( x[d][ch] + sum_src x[src][ch] ), ch<11
__global__ void k_agg11(const float* __restrict__ x, const int* __restrict__ srcidx,
                        const int* __restrict__ row_ptr, bf16* __restrict__ a1b)
{
    long gid = (long)blockIdx.x * 256 + threadIdx.x;
    if (gid >= (long)kSeg * 32) return;
    int ch  = (int)(gid & 31);
    int seg = (int)(gid >> 5);
    int d = seg >> 2, r = seg & 3;
    float acc = 0.f;
    if (ch < 11) {
        acc = x[(long)d * 11 + ch];
        int i0 = row_ptr[seg], i1 = row_ptr[seg + 1];
        for (int i = i0; i < i1; ++i) acc += x[(long)srcidx[i] * 11 + ch];
    }
    a1b[((long)r * kN + d) * 32 + ch] = (bf16)acc;
}

// x [N,11] fp32 -> xb1F frag-linear (KSR=4), k=11..127 zero-padded
__global__ void k_xpad(const float* __restrict__ x, bf16* __restrict__ xb1F)
{
    long gid = (long)blockIdx.x * 256 + threadIdx.x;
    if (gid >= (long)kN * 128) return;
    int c = (int)(gid & 127); int d = (int)(gid >> 7);
    long idx = ((long)(d >> 4) * 4 + (c >> 5)) * 512
             + ((c >> 3) & 3) * 128 + (d & 15) * 8 + (c & 7);
    xb1F[idx] = (c < 11) ? (bf16)x[(long)d * 11 + c] : (bf16)0.f;
}

// weight transpose-pack: in [K,N] fp32 -> out[n*ldout + coff + k] bf16
// (used for w1t consumed by k_rgin1's strided reg loads)
__global__ void k_wt_s(const float* __restrict__ in, bf16* __restrict__ out,
                       int K, int N, int ldout, int coff)
{
    int i = blockIdx.x * 256 + threadIdx.x;
    if (i >= K * N) return;
    int n = i / K, k = i - n * K;
    out[(long)n * ldout + coff + k] = (bf16)in[(long)k * N + n];
}

// fragment-linear B pack: element (n,k) -> blk*512 + lq*128 + l15*8 + u,
// blk = ((n>>6)*4 + ((n>>4)&3))*KS + (k>>5).
__global__ void k_wt_f(const float* __restrict__ in, bf16* __restrict__ out,
                       int Kin, int k0, int KS)
{
    int i = blockIdx.x * 256 + threadIdx.x;
    if (i >= Kin * 256) return;
    int n = i & 255, krel = i >> 8;
    int k = k0 + krel;
    int blk = ((n >> 6) * 4 + ((n >> 4) & 3)) * KS + (k >> 5);
    int idx = blk * 512 + ((k >> 3) & 3) * 128 + (n & 15) * 8 + (k & 7);
    out[idx] = (bf16)in[(long)krel * 256 + n];
}

// scaled fragment-linear B pack: out = bf16( in[krel][n] * s[krel] )  (w2' = scl*w2)
__global__ void k_wt_fs(const float* __restrict__ in, const float* __restrict__ s,
                        bf16* __restrict__ out, int Kin, int k0, int KS)
{
    int i = blockIdx.x * 256 + threadIdx.x;
    if (i >= Kin * 256) return;
    int n = i & 255, krel = i >> 8;
    int k = k0 + krel;
    int blk = ((n >> 6) * 4 + ((n >> 4) & 3)) * KS + (k >> 5);
    int idx = blk * 512 + ((k >> 3) & 3) * 128 + (n & 15) * 8 + (k & 7);
    out[idx] = (bf16)(in[(long)krel * 256 + n] * s[krel]);
}

// layer-1 w1 pack: [4][11][256] fp32 -> [4][256][32] bf16 zero-padded
__global__ void k_wtL1(const float* __restrict__ w1, bf16* __restrict__ out)
{
    int i = blockIdx.x * 256 + threadIdx.x;
    if (i >= 4 * 256 * 32) return;
    int r = i >> 13, rem = i & 8191, n = rem >> 5, k = rem & 31;
    out[i] = (k < 11) ? (bf16)w1[(long)r * 11 * 256 + (long)k * 256 + n] : (bf16)0.f;
}

// BN params: scl = g*rsqrt(var+eps) (>0 since g=ones); u = bt/scl - mu so that
// relu(h*scl+shf) = scl*max(h+u,0), folding scl into w2 (k_wt_fs).
__global__ void k_bn_params(const float* __restrict__ stats,
                            const float* __restrict__ g, const float* __restrict__ bt,
                            float* __restrict__ scl, float* __restrict__ uu)
{
    int c = blockIdx.x * 256 + threadIdx.x;  // < 1024
    const float invN = 1.0f / (float)kN;
    float mu  = stats[c] * invN;
    float var = stats[1024 + c] * invN - mu * mu;
    float sc  = g[c] * rsqrtf(var + 1e-5f);
    scl[c] = sc;
    uu[c]  = bt[c] / sc - mu;
}

__global__ void k_bias_total(const float* sb0, const float* b20,
                             const float* sb1, const float* b21,
                             const float* sb2, const float* b22,
                             float* __restrict__ btt)
{
    int l = blockIdx.x, j = threadIdx.x;
    const float* sb = (l == 0) ? sb0 : (l == 1) ? sb1 : sb2;
    const float* b2 = (l == 0) ? b20 : (l == 1) ? b21 : b22;
    float v = sb[j];
#pragma unroll
    for (int r = 0; r < 4; ++r) v += b2[r * 256 + j];
    btt[l * 256 + j] = v;
}

__global__ void k_counts(const int* __restrict__ batch, float* __restrict__ counts)
{
    int v = blockIdx.x * 256 + threadIdx.x;
    if (v < kN) atomicAdd(&counts[batch[v]], 1.0f);
}

__global__ __launch_bounds__(64) void k_head(const float* __restrict__ pooled,
                                             const float* __restrict__ counts,
                                             const float* __restrict__ lw,
                                             const float* __restrict__ lb,
                                             float* __restrict__ out)
{
    int g = blockIdx.x;
    int l = threadIdx.x;
    float inv = 1.0f / fmaxf(counts[g], 1.0f);
    float acc[kT];
#pragma unroll
    for (int t = 0; t < kT; ++t) acc[t] = 0.f;
    for (int k = l; k < 256; k += 64) {
        float p = pooled[((long)g << 8) + k] * inv;
#pragma unroll
        for (int t = 0; t < kT; ++t) acc[t] = fmaf(p, lw[k * kT + t], acc[t]);
    }
#pragma unroll
    for (int off = 32; off > 0; off >>= 1)
#pragma unroll
        for (int t = 0; t < kT; ++t) acc[t] += __shfl_down(acc[t], off);
    if (l == 0) {
#pragma unroll
        for (int t = 0; t < kT; ++t) out[(long)g * kT + t] = acc[t] + lb[t];
    }
}

// ---------------------------------------------------------------------------
extern "C" void kernel_launch(void* const* d_in, const int* in_sizes, int n_in,
                              void* d_out, int out_size, void* d_ws, size_t ws_size,
                              hipStream_t stream)
{
    const float* x     = (const float*)d_in[0];
    const int*   ei    = (const int*)d_in[1];
    const int*   et    = (const int*)d_in[2];
    const int*   batch = (const int*)d_in[3];

    const float *sw[3], *sb[3], *w1[3], *gmm[3], *btm[3], *w2[3], *b2[3];
    for (int l = 0; l < 3; ++l) {
        int b = 4 + l * 8;
        sw[l]  = (const float*)d_in[b + 0];
        sb[l]  = (const float*)d_in[b + 1];
        w1[l]  = (const float*)d_in[b + 2];
        // b+3 = b1 (cancels inside BatchNorm)
        gmm[l] = (const float*)d_in[b + 4];
        btm[l] = (const float*)d_in[b + 5];
        w2[l]  = (const float*)d_in[b + 6];
        b2[l]  = (const float*)d_in[b + 7];
    }
    const float* lin_w = (const float*)d_in[28];
    const float* lin_b = (const float*)d_in[29];
    float* out = (float*)d_out;
    (void)in_sizes; (void)n_in; (void)out_size;

    // ---- workspace (~190 MB) ----
    const int kPanels = 3128;  // ceil(50048/16): covers 128-tile overrun
    char* wsb = (char*)d_ws;
    size_t off = 0;
    auto alloc = [&](size_t bytes) { void* p = wsb + off; off = (off + bytes + 255) & ~(size_t)255; return p; };
    bf16*  Pb0    = (bf16*) alloc((size_t)kN * 256 * 2);
    bf16*  Pb1    = (bf16*) alloc((size_t)kN * 256 * 2);
    bf16*  h1F    = (bf16*) alloc((size_t)kPanels * 32 * 512 * 2);  // frag-linear
    bf16*  a1b    = (bf16*) alloc((size_t)4 * kN * 32 * 2);
    bf16*  xb1F   = (bf16*) alloc((size_t)kPanels * 4 * 512 * 2);   // frag-linear
    bf16*  w1t    = (bf16*) alloc((size_t)2 * 4 * 65536 * 2);   // layers 2,3
    bf16*  w1tL1  = (bf16*) alloc((size_t)4 * 256 * 32 * 2);
    bf16*  Bc0    = (bf16*) alloc((size_t)256 * 1152 * 2);      // frag-linear [sw_pad128 | w2']
    bf16*  Bc1    = (bf16*) alloc((size_t)256 * 1280 * 2);
    bf16*  Bc2    = (bf16*) alloc((size_t)256 * 1280 * 2);
    int*   hist   = (int*)  alloc((size_t)(kSeg + 1) * 4);
    int*   row_ptr= (int*)  alloc((size_t)(kSeg + 1) * 4);
    int*   cursor = (int*)  alloc((size_t)kSeg * 4);
    int*   srcidx = (int*)  alloc((size_t)kE * 4);
    int*   bsum   = (int*)  alloc((size_t)kScanB * 4);
    int*   boff   = (int*)  alloc((size_t)kScanB * 4);
    float* stats  = (float*)alloc(2048 * 4);
    float* scl    = (float*)alloc(1024 * 4);
    float* uu     = (float*)alloc(1024 * 4);
    float* btt    = (float*)alloc(3 * 256 * 4);
    float* pooled = (float*)alloc((size_t)kG * 256 * 4);
    float* counts = (float*)alloc(kG * 4);
    if (ws_size < off) return;  // clean absmax-fail instead of OOB crash

    const dim3 gL1((kN + 127) / 128, 4);  // l1 GEMM grid (512 thr)
    const dim3 gR((kN + 63) / 64, 4);     // rgin grid (512 thr, M-tile 64)
    const dim3 g2((kN + 127) / 128, 2);   // GEMM2 grid (256 thr, 128x128 tile)

    // ---- CSR build (parallel scan) + weight prepack ----
    hipMemsetAsync(hist, 0, (size_t)(kSeg + 1) * 4, stream);
    k_hist<<<(kE + 255) / 256, 256, 0, stream>>>(ei, et, hist);
    k_scan1<<<kScanB, 256, 0, stream>>>(hist, bsum);
    k_scan2<<<1, 1024, 0, stream>>>(bsum, boff);
    k_scan3<<<kScanB, 256, 0, stream>>>(hist, boff, row_ptr, cursor);
    k_fill<<<(kE + 255) / 256, 256, 0, stream>>>(ei, et, cursor, srcidx);

    k_bias_total<<<3, 256, 0, stream>>>(sb[0], b2[0], sb[1], b2[1], sb[2], b2[2], btt);
    k_xpad<<<(int)(((long)kN * 128 + 255) / 256), 256, 0, stream>>>(x, xb1F);
    k_wtL1<<<(4 * 256 * 32 + 255) / 256, 256, 0, stream>>>(w1[0], w1tL1);
    for (int l = 1; l < 3; ++l)
        for (int r = 0; r < 4; ++r)
            k_wt_s<<<256, 256, 0, stream>>>(w1[l] + (long)r * 65536,
                                            w1t + (long)(l - 1) * 4 * 65536 + (long)r * 65536,
                                            256, 256, 256, 0);
    // frag-linear B packs, sw (unscaled) parts only; w2' packed in-path after stats
    hipMemsetAsync(Bc0, 0, (size_t)256 * 1152 * 2, stream);
    k_wt_f<<<(11 * 256 + 255) / 256, 256, 0, stream>>>(sw[0], Bc0, 11, 0, 36);
    k_wt_f<<<256, 256, 0, stream>>>(sw[1], Bc1, 256, 0, 40);
    k_wt_f<<<256, 256, 0, stream>>>(sw[2], Bc2, 256, 0, 40);

    k_counts<<<(kN + 255) / 256, 256, 0, stream>>>(batch, counts);  // counts poisoned -> must init
    hipMemsetAsync(pooled, 0, (size_t)kG * 256 * 4, stream);

    // ---------------- layer 1 ----------------
    k_agg11<<<(int)(((long)kSeg * 32 + 255) / 256), 256, 0, stream>>>(x, srcidx, row_ptr, a1b);
    hipMemsetAsync(stats, 0, 2048 * 4, stream);
    k_l1gemm<<<gL1, 512, 0, stream>>>(a1b, w1tL1, h1F, stats);
    k_bn_params<<<4, 256, 0, stream>>>(stats, gmm[0], btm[0], scl, uu);
    k_wt_fs<<<1024, 256, 0, stream>>>(w2[0], scl, Bc0, 1024, 128, 36);
    k_gemm2<36, 4, false, false><<<g2, 256, 0, stream>>>(xb1F, h1F, Bc0,
                                                         Pb0, kN, btt + 0, uu, nullptr, nullptr);

    // ---------------- layer 2 ----------------
    hipMemsetAsync(stats, 0, 2048 * 4, stream);
    k_rgin1<<<gR, 512, 0, stream>>>(Pb0, srcidx, row_ptr, w1t, h1F, stats);
    k_bn_params<<<4, 256, 0, stream>>>(stats, gmm[1], btm[1], scl, uu);
    k_wt_fs<<<1024, 256, 0, stream>>>(w2[1], scl, Bc1, 1024, 256, 40);
    k_gemm2<40, 8, true, false><<<g2, 256, 0, stream>>>(Pb0, h1F, Bc1,
                                                        Pb1, kN, btt + 256, uu, nullptr, nullptr);

    // ---------------- layer 3 (pool fused into GEMM2) ----------------
    hipMemsetAsync(stats, 0, 2048 * 4, stream);
    k_rgin1<<<gR, 512, 0, stream>>>(Pb1, srcidx, row_ptr, w1t + (size_t)4 * 65536, h1F, stats);
    k_bn_params<<<4, 256, 0, stream>>>(stats, gmm[2], btm[2], scl, uu);
    k_wt_fs<<<1024, 256, 0, stream>>>(w2[2], scl, Bc2, 1024, 256, 40);
    k_gemm2<40, 8, true, true><<<g2, 256, 0, stream>>>(Pb1, h1F, Bc2,
                                                       nullptr, kN, btt + 512, uu, batch, pooled);

    // ---------------- head ----------------
    k_head<<<kG, 64, 0, stream>>>(pooled, counts, lin_w, lin_b, out);
}